// Round 15
// baseline (896.795 us; speedup 1.0000x reference)
//
#include <hip/hip_runtime.h>
#include <cstdint>
#include <cstddef>

#define N_NODES 100000
#define N_EDGES 1600000
#define F_INDIM 128
#define HDIM 256
#define C_OUT 40
#define BN_EPS 1e-5f

#define NBUCK 196            // ceil(N_NODES / 512)
#define BCAP 10240           // bucket capacity: mean 8192, 22 sigma headroom

typedef unsigned short bf16_t;
typedef __attribute__((ext_vector_type(8))) short bf16x8;
typedef __attribute__((ext_vector_type(4))) float f32x4;

__device__ __forceinline__ float bf2f(unsigned int u) {
  return __uint_as_float(u << 16);
}
__device__ __forceinline__ bf16_t f2bf(float f) {
  unsigned int x = __float_as_uint(f);
  return (bf16_t)((x + 0x7fffu + ((x >> 16) & 1u)) >> 16);
}

// ---------------- f32 -> bf16 conversion (n % 4 == 0) ----------------
__global__ void k_cvt(const float* __restrict__ s, bf16_t* __restrict__ d, int n) {
  int i = (blockIdx.x * blockDim.x + threadIdx.x) * 4;
  if (i >= n) return;
  float4 v = *reinterpret_cast<const float4*>(&s[i]);
  uint2 o;
  o.x = (unsigned)f2bf(v.x) | ((unsigned)f2bf(v.y) << 16);
  o.y = (unsigned)f2bf(v.z) | ((unsigned)f2bf(v.w) << 16);
  *reinterpret_cast<uint2*>(&d[i]) = o;
}

// merged conversion of the 5 weight tensors (one launch)
#define W0N 32768            // pre_w 256*128
#define W1N 196608           // lin_l_w 3*256*256
#define W2N 196608           // lin_r_w
#define W3N 65536            // post1_w
#define W4N 10240            // post2_w 40*256
#define WTOT (W0N + W1N + W2N + W3N + W4N)

__global__ void k_cvt_w(const float* __restrict__ s0, bf16_t* __restrict__ d0,
                        const float* __restrict__ s1, bf16_t* __restrict__ d1,
                        const float* __restrict__ s2, bf16_t* __restrict__ d2,
                        const float* __restrict__ s3, bf16_t* __restrict__ d3,
                        const float* __restrict__ s4, bf16_t* __restrict__ d4) {
  int i = (blockIdx.x * blockDim.x + threadIdx.x) * 4;
  if (i >= WTOT) return;
  const float* s; bf16_t* d;
  if (i < W0N)                         { s = s0; d = d0; }
  else if (i < W0N + W1N)              { s = s1; d = d1; i -= W0N; }
  else if (i < W0N + W1N + W2N)        { s = s2; d = d2; i -= W0N + W1N; }
  else if (i < W0N + W1N + W2N + W3N)  { s = s3; d = d3; i -= W0N + W1N + W2N; }
  else                                 { s = s4; d = d4; i -= W0N + W1N + W2N + W3N; }
  float4 v = *reinterpret_cast<const float4*>(&s[i]);
  uint2 o;
  o.x = (unsigned)f2bf(v.x) | ((unsigned)f2bf(v.y) << 16);
  o.y = (unsigned)f2bf(v.z) | ((unsigned)f2bf(v.w) << 16);
  *reinterpret_cast<uint2*>(&d[i]) = o;
}

// ---------------- CSR build: bucketed two-phase (kills write amplification) -
// Phase C: per-edge -> node histogram (atomic) + append (src,dst) pair to the
// dst-bucket's region (sequential cursor -> dense line fills, ~1x write amp).
// Phase D: one block per bucket; LDS rank counters; csr writes land inside the
// bucket's ~32 KB csr window -> dense L2 line fills.
__global__ void k_scatter(const int* __restrict__ src, const int* __restrict__ dst,
                          int* __restrict__ cnt, int* __restrict__ bcur,
                          uint2* __restrict__ bpairs, int E) {
  for (int e = blockIdx.x * blockDim.x + threadIdx.x; e < E; e += gridDim.x * blockDim.x) {
    int d = dst[e];
    int s = src[e];
    atomicAdd(&cnt[d], 1);
    int b = d >> 9;
    int pos = atomicAdd(&bcur[b * 16], 1);     // stride 16 ints: one line per cursor
    if (pos < BCAP)
      bpairs[(size_t)b * BCAP + pos] = make_uint2((unsigned)s, (unsigned)d);
  }
}

__global__ __launch_bounds__(512)
void k_bsort(const uint2* __restrict__ bpairs, const int* __restrict__ row_ptr,
             int* __restrict__ csr, int n) {
  __shared__ int lcur[512];
  __shared__ int lrp[512];
  int b = blockIdx.x;
  int n0 = b << 9;
  int n1 = n0 + 512; if (n1 > n) n1 = n;
  int tid = threadIdx.x;
  lcur[tid] = 0;
  lrp[tid] = (n0 + tid < n1) ? row_ptr[n0 + tid] : 0;
  __syncthreads();
  int base = lrp[0];
  int bs = row_ptr[n1] - base;
  if (bs > BCAP) bs = BCAP;                    // matches scatter's drop guard
  const uint2* bp = &bpairs[(size_t)b * BCAP];
  for (int i = tid; i < bs; i += 512) {
    uint2 p = bp[i];
    int d = (int)p.y;
    int r = atomicAdd(&lcur[d - n0], 1);
    csr[lrp[d - n0] + r] = (int)p.x;
  }
}

__global__ __launch_bounds__(1024)
void k_scan_local(const int* __restrict__ cnt, int* __restrict__ row_ptr,
                  int* __restrict__ blk_sum, int n) {
  __shared__ int buf[1024];
  int tid = threadIdx.x;
  int i = blockIdx.x * 1024 + tid;
  int v = (i < n) ? cnt[i] : 0;
  buf[tid] = v;
  __syncthreads();
  for (int off = 1; off < 1024; off <<= 1) {
    int t = (tid >= off) ? buf[tid - off] : 0;
    __syncthreads();
    buf[tid] += t;
    __syncthreads();
  }
  if (i < n) row_ptr[i] = buf[tid] - v;       // block-local exclusive
  if (tid == 1023) blk_sum[blockIdx.x] = buf[1023];
}

__global__ __launch_bounds__(128)
void k_scan_blk(const int* __restrict__ blk_sum, int* __restrict__ blk_off, int nb) {
  __shared__ int buf[128];
  int tid = threadIdx.x;
  int v = (tid < nb) ? blk_sum[tid] : 0;
  buf[tid] = v;
  __syncthreads();
  for (int off = 1; off < 128; off <<= 1) {
    int t = (tid >= off) ? buf[tid - off] : 0;
    __syncthreads();
    buf[tid] += t;
    __syncthreads();
  }
  if (tid < nb) blk_off[tid] = buf[tid] - v;  // exclusive
}

// adds block offsets AND computes inv_deg (folded k_inv)
__global__ void k_scan_add(int* __restrict__ row_ptr, const int* __restrict__ blk_off,
                           const int* __restrict__ cnt, float* __restrict__ inv, int n) {
  int i = blockIdx.x * blockDim.x + threadIdx.x;
  if (i < n) {
    row_ptr[i] += blk_off[i >> 10];
    int c = cnt[i];
    inv[i] = 1.0f / (float)(c > 0 ? c : 1);
  }
  if (i == 0) row_ptr[n] = N_EDGES;
}

// ---------------- mean aggregation ----------------
__device__ __forceinline__ void add8(float* acc, uint4 r) {
  acc[0] += bf2f(r.x & 0xffffu); acc[1] += bf2f(r.x >> 16);
  acc[2] += bf2f(r.y & 0xffffu); acc[3] += bf2f(r.y >> 16);
  acc[4] += bf2f(r.z & 0xffffu); acc[5] += bf2f(r.z >> 16);
  acc[6] += bf2f(r.w & 0xffffu); acc[7] += bf2f(r.w >> 16);
}

__global__ __launch_bounds__(256)
void k_aggregate(const bf16_t* __restrict__ h, const int* __restrict__ row_ptr,
                 const int* __restrict__ csr, const float* __restrict__ inv_deg,
                 bf16_t* __restrict__ mean) {
  int w = threadIdx.x >> 6, lane = threadIdx.x & 63;
  int node = blockIdx.x * 4 + w;
  if (node >= N_NODES) return;
  int beg = row_ptr[node], end = row_ptr[node + 1];
  int half = lane >> 5;         // 0 or 1: which edge of the pair
  int l32 = lane & 31;          // 16B column block within the row
  float acc[8] = {};
  int deg = end - beg;
  int p = beg;
  int p8 = beg + (deg & ~7);
  for (; p < p8; p += 8) {       // 8 edges per iteration, 4 row loads/lane in flight
    int s0 = csr[p + half];
    int s1 = csr[p + 2 + half];
    int s2 = csr[p + 4 + half];
    int s3 = csr[p + 6 + half];
    uint4 r0 = *reinterpret_cast<const uint4*>(&h[(size_t)s0 * HDIM + l32 * 8]);
    uint4 r1 = *reinterpret_cast<const uint4*>(&h[(size_t)s1 * HDIM + l32 * 8]);
    uint4 r2 = *reinterpret_cast<const uint4*>(&h[(size_t)s2 * HDIM + l32 * 8]);
    uint4 r3 = *reinterpret_cast<const uint4*>(&h[(size_t)s3 * HDIM + l32 * 8]);
    add8(acc, r0);
    add8(acc, r1);
    add8(acc, r2);
    add8(acc, r3);
  }
  if (end - p >= 4) {            // 4-edge block: 2 row loads in flight
    int s0 = csr[p + half];
    int s1 = csr[p + 2 + half];
    uint4 r0 = *reinterpret_cast<const uint4*>(&h[(size_t)s0 * HDIM + l32 * 8]);
    uint4 r1 = *reinterpret_cast<const uint4*>(&h[(size_t)s1 * HDIM + l32 * 8]);
    add8(acc, r0);
    add8(acc, r1);
    p += 4;
  }
  for (; p < end; p += 2) {      // tail: <=3 edges, pair-guarded
    int e = p + half;
    if (e < end) {
      int s = csr[e];
      uint4 r = *reinterpret_cast<const uint4*>(&h[(size_t)s * HDIM + l32 * 8]);
      add8(acc, r);
    }
  }
#pragma unroll
  for (int k = 0; k < 8; ++k) acc[k] += __shfl_xor(acc[k], 32);
  if (half == 0) {
    float iv = inv_deg[node];
    uint4 o;
    o.x = (unsigned)f2bf(acc[0] * iv) | ((unsigned)f2bf(acc[1] * iv) << 16);
    o.y = (unsigned)f2bf(acc[2] * iv) | ((unsigned)f2bf(acc[3] * iv) << 16);
    o.z = (unsigned)f2bf(acc[4] * iv) | ((unsigned)f2bf(acc[5] * iv) << 16);
    o.w = (unsigned)f2bf(acc[6] * iv) | ((unsigned)f2bf(acc[7] * iv) << 16);
    *reinterpret_cast<uint4*>(&mean[(size_t)node * HDIM + l32 * 8]) = o;
  }
}

// ---------------- output store helpers ----------------
__device__ __forceinline__ void store1(float* p, float v) { *p = v; }
__device__ __forceinline__ void store1(bf16_t* p, float v) { *p = f2bf(v); }

// ---------------- bf16 MFMA GEMM, gload_lds + XOR slot-swizzle --------------
// C[M,OUT] = act( A0 @ W0^T (+ A1 @ W1^T) + bias ), W row-major [OUT,K] bf16.
// 128x128 tile, BK=32, 4 waves (2x2), 4x4 frags of 16x16x32 per wave.
// Grid: 1-D. For OUT=256 the two column-tiles of row-panel x are placed 8
// dispatch slots apart -> same XCD under round-robin -> A panel read once
// into that XCD's L2 (T1 co-location). For OUT<=128: g == row tile.
// LDS slot-swizzle: same involution on source k-slot and read slot (rule #21).
template <typename TOUT>
__global__ __launch_bounds__(256)
void gemm_mfma(const bf16_t* __restrict__ A0, const bf16_t* __restrict__ W0,
               const bf16_t* __restrict__ A1, const bf16_t* __restrict__ W1,
               const float* __restrict__ bias, const float* __restrict__ bn,
               TOUT* __restrict__ C, int M, int K, int OUT, int dual) {
  __shared__ bf16_t lds[2][2][128 * 32];   // [buf][A/B][row*32+k]
  int g = blockIdx.x, bx, by;
  if (OUT > 128) {                // co-locate (x,0) and (x,1): slots g and g+8
    int grp = g >> 4, loc = g & 15;
    bx = grp * 8 + (loc & 7);
    by = loc >> 3;
  } else {
    bx = g; by = 0;
  }
  const int row0 = bx * 128, col0 = by * 128;
  if (row0 >= M) return;          // uniform per block (pad blocks)

  const int tid = threadIdx.x;
  const int lane = tid & 63, wid = tid >> 6;
  const int wm = wid >> 1, wn = wid & 1;
  const int l15 = lane & 15, l4 = lane >> 4;

  const int nk = K / 32;
  const int nsteps = dual ? nk * 2 : nk;

  f32x4 acc[4][4] = {};

  const int srow_base = wid * 32 + (lane >> 2);
  const int skk = ((lane & 3) ^ ((lane >> 3) & 3)) * 8;   // swizzled source k-slot

  auto stage = [&](int s, int b) {
    const bf16_t* A = (s < nk) ? A0 : A1;
    const bf16_t* W = (s < nk) ? W0 : W1;
    int kk0 = ((s < nk) ? s : s - nk) * 32 + skk;
#pragma unroll
    for (int c = 0; c < 2; ++c) {
      int chunk = wid * 2 + c;            // 0..7
      int row = srow_base + c * 16;       // chunk*16 + lane/4
      int ar = row0 + row; if (ar >= M) ar = M - 1;
      int br = col0 + row; if (br >= OUT) br = OUT - 1;
      __builtin_amdgcn_global_load_lds(
          (const __attribute__((address_space(1))) unsigned int*)&A[(size_t)ar * K + kk0],
          (__attribute__((address_space(3))) unsigned int*)&lds[b][0][chunk * 512],
          16, 0, 0);
      __builtin_amdgcn_global_load_lds(
          (const __attribute__((address_space(1))) unsigned int*)&W[(size_t)br * K + kk0],
          (__attribute__((address_space(3))) unsigned int*)&lds[b][1][chunk * 512],
          16, 0, 0);
    }
  };

  const int rslot = (l4 ^ ((l15 >> 1) & 3)) * 8;

  stage(0, 0);
  __syncthreads();               // drains vmcnt(0): buffer 0 ready
  int cur = 0;
  for (int s = 0; s < nsteps; ++s) {
    if (s + 1 < nsteps) stage(s + 1, cur ^ 1);   // async into other buffer
    const bf16_t* pa = &lds[cur][0][l15 * 32 + rslot];
    const bf16_t* pb = &lds[cur][1][l15 * 32 + rslot];
    bf16x8 a[4], b[4];
#pragma unroll
    for (int i = 0; i < 4; ++i)
      a[i] = *reinterpret_cast<const bf16x8*>(&pa[(wm * 64 + i * 16) * 32]);
#pragma unroll
    for (int j = 0; j < 4; ++j)
      b[j] = *reinterpret_cast<const bf16x8*>(&pb[(wn * 64 + j * 16) * 32]);
#pragma unroll
    for (int i = 0; i < 4; ++i)
#pragma unroll
      for (int j = 0; j < 4; ++j)
        acc[i][j] = __builtin_amdgcn_mfma_f32_16x16x32_bf16(a[i], b[j], acc[i][j], 0, 0, 0);
    if (s + 1 < nsteps) {
      __syncthreads();           // all reads of cur done AND staged buffer drained
      cur ^= 1;
    }
  }

  // epilogue: C/D frag mapping col=lane&15, row=(lane>>4)*4+reg  [m89]
#pragma unroll
  for (int j = 0; j < 4; ++j) {
    int col = col0 + wn * 64 + j * 16 + l15;
    if (col >= OUT) continue;
    float bs = bias ? bias[col] : 0.f;
    float scale = 1.f, shift = bs;
    bool has_bn = (bn != nullptr);
    if (has_bn) {
      float g2 = bn[col], bb = bn[256 + col], mm = bn[512 + col], vv = bn[768 + col];
      float is = g2 * rsqrtf(vv + BN_EPS);
      scale = is; shift = (bs - mm) * is + bb;
    }
#pragma unroll
    for (int i = 0; i < 4; ++i) {
#pragma unroll
      for (int r = 0; r < 4; ++r) {
        int row = row0 + wm * 64 + i * 16 + l4 * 4 + r;
        if (row >= M) continue;
        float v = acc[i][j][r];
        v = has_bn ? fmaxf(v * scale + shift, 0.f) : (v + bs);
        store1(&C[(size_t)row * OUT + col], v);
      }
    }
  }
}

// ---------------- row log-softmax (C=40) ----------------
__global__ __launch_bounds__(256)
void k_logsoftmax(const float* __restrict__ logits, float* __restrict__ out, int M) {
  int row = blockIdx.x * 4 + (threadIdx.x >> 6);
  if (row >= M) return;
  int lane = threadIdx.x & 63;
  float v = (lane < C_OUT) ? logits[(size_t)row * C_OUT + lane] : -1e30f;
  float m = v;
#pragma unroll
  for (int o = 32; o; o >>= 1) m = fmaxf(m, __shfl_xor(m, o));
  float e = (lane < C_OUT) ? expf(v - m) : 0.f;
  float s = e;
#pragma unroll
  for (int o = 32; o; o >>= 1) s += __shfl_xor(s, o);
  if (lane < C_OUT) out[(size_t)row * C_OUT + lane] = v - m - logf(s);
}

// ---------------- host launch ----------------
extern "C" void kernel_launch(void* const* d_in, const int* in_sizes, int n_in,
                              void* d_out, int out_size, void* d_ws, size_t ws_size,
                              hipStream_t stream) {
  const float* x       = (const float*)d_in[0];
  const int*   ei      = (const int*)d_in[1];   // [2, E] int32
  const float* pre_w   = (const float*)d_in[2];
  const float* pre_b   = (const float*)d_in[3];
  const float* bn      = (const float*)d_in[4]; // [5,4,256]
  const float* lin_l_w = (const float*)d_in[5];
  const float* lin_l_b = (const float*)d_in[6];
  const float* lin_r_w = (const float*)d_in[7];
  const float* post1_w = (const float*)d_in[8];
  const float* post1_b = (const float*)d_in[9];
  const float* post2_w = (const float*)d_in[10];
  const float* post2_b = (const float*)d_in[11];
  float* out = (float*)d_out;

  const int* src = ei;
  const int* dstv = ei + N_EDGES;

  char* base = (char*)d_ws;
  size_t off = 0;
  auto alloc = [&](size_t bytes) -> void* {
    void* p = base + off;
    off = (off + bytes + 255) & ~(size_t)255;
    return p;
  };
  bf16_t* hA = (bf16_t*)alloc((size_t)N_NODES * HDIM * 2);
  bf16_t* hB = (bf16_t*)alloc((size_t)N_NODES * HDIM * 2);  // x_bf16 pre-GEMM, f32 logits post
  bf16_t* hC = (bf16_t*)alloc((size_t)N_NODES * HDIM * 2);
  int* row_ptr = (int*)alloc((size_t)(N_NODES + 1) * 4);
  int* cnt     = (int*)alloc((size_t)N_NODES * 4);
  int* csr     = (int*)alloc((size_t)N_EDGES * 4);
  uint2* bpairs = (uint2*)alloc((size_t)NBUCK * BCAP * 8);
  int* bcur    = (int*)alloc((size_t)NBUCK * 16 * 4);
  float* inv   = (float*)alloc((size_t)N_NODES * 4);
  int* blk_sum = (int*)alloc(128 * 4);
  int* blk_off = (int*)alloc(128 * 4);
  bf16_t* w_pre = (bf16_t*)alloc((size_t)HDIM * F_INDIM * 2);
  bf16_t* w_ll  = (bf16_t*)alloc((size_t)3 * HDIM * HDIM * 2);
  bf16_t* w_lr  = (bf16_t*)alloc((size_t)3 * HDIM * HDIM * 2);
  bf16_t* w_p1  = (bf16_t*)alloc((size_t)HDIM * HDIM * 2);
  bf16_t* w_p2  = (bf16_t*)alloc((size_t)C_OUT * HDIM * 2);
  (void)n_in; (void)in_sizes; (void)out_size;
  if (off > ws_size) return;  // visible failure (zeros), no fault

  bf16_t* x_bf = hB;

  // input + weight conversions (x separate; 5 weights merged into one launch)
  {
    int n = N_NODES * F_INDIM;
    k_cvt<<<(n / 4 + 255) / 256, 256, 0, stream>>>(x, x_bf, n);
    k_cvt_w<<<(WTOT / 4 + 255) / 256, 256, 0, stream>>>(
        pre_w, w_pre, lin_l_w, w_ll, lin_r_w, w_lr, post1_w, w_p1, post2_w, w_p2);
  }

  // CSR build: scatter (hist + bucket append), scan (+inv), bucket sort
  hipMemsetAsync(cnt, 0, (size_t)N_NODES * 4, stream);
  hipMemsetAsync(bcur, 0, (size_t)NBUCK * 16 * 4, stream);
  k_scatter<<<2048, 256, 0, stream>>>(src, dstv, cnt, bcur, bpairs, N_EDGES);
  int nb = (N_NODES + 1023) / 1024;  // 98
  k_scan_local<<<nb, 1024, 0, stream>>>(cnt, row_ptr, blk_sum, N_NODES);
  k_scan_blk<<<1, 128, 0, stream>>>(blk_sum, blk_off, nb);
  k_scan_add<<<(N_NODES + 255) / 256, 256, 0, stream>>>(row_ptr, blk_off, cnt, inv, N_NODES);
  k_bsort<<<NBUCK, 512, 0, stream>>>(bpairs, row_ptr, csr, N_NODES);

  // grids: OUT=256 -> 1-D swizzled (98 groups x 16); OUT=40 -> plain 782
  int nrt = (N_NODES + 127) / 128;          // 782
  int gW = ((nrt + 7) / 8) * 16;            // 1568
  // pre: h = relu(bn0(x @ pre_w^T + pre_b))
  gemm_mfma<bf16_t><<<gW, 256, 0, stream>>>(
      x_bf, w_pre, nullptr, nullptr, pre_b, bn, hA, N_NODES, F_INDIM, HDIM, 0);

  bf16_t* hcur = hA;
  bf16_t* hnext = hC;
  for (int i = 0; i < 3; ++i) {
    k_aggregate<<<N_NODES / 4, 256, 0, stream>>>(hcur, row_ptr, csr, inv, hB);
    gemm_mfma<bf16_t><<<gW, 256, 0, stream>>>(
        hB, w_ll + (size_t)i * HDIM * HDIM,
        hcur, w_lr + (size_t)i * HDIM * HDIM,
        lin_l_b + (size_t)i * HDIM,
        bn + (size_t)(i + 1) * 4 * HDIM,
        hnext, N_NODES, HDIM, HDIM, 1);
    bf16_t* t = hcur; hcur = hnext; hnext = t;
  }
  // post1
  gemm_mfma<bf16_t><<<gW, 256, 0, stream>>>(
      hcur, w_p1, nullptr, nullptr, post1_b,
      bn + (size_t)4 * 4 * HDIM, hnext, N_NODES, HDIM, HDIM, 0);
  // post2 -> f32 logits (no bn); hB is free now
  float* logits = (float*)hB;
  gemm_mfma<float><<<nrt, 256, 0, stream>>>(
      hnext, w_p2, nullptr, nullptr, post2_b,
      nullptr, logits, N_NODES, HDIM, C_OUT, 0);
  k_logsoftmax<<<(N_NODES + 3) / 4, 256, 0, stream>>>(logits, out, N_NODES);
}

// Round 16
// 741.543 us; speedup vs baseline: 1.2094x; 1.2094x over previous
//
#include <hip/hip_runtime.h>
#include <cstdint>
#include <cstddef>

#define N_NODES 100000
#define N_EDGES 1600000
#define F_INDIM 128
#define HDIM 256
#define C_OUT 40
#define BN_EPS 1e-5f

typedef unsigned short bf16_t;
typedef __attribute__((ext_vector_type(8))) short bf16x8;
typedef __attribute__((ext_vector_type(4))) float f32x4;

__device__ __forceinline__ float bf2f(unsigned int u) {
  return __uint_as_float(u << 16);
}
__device__ __forceinline__ bf16_t f2bf(float f) {
  unsigned int x = __float_as_uint(f);
  return (bf16_t)((x + 0x7fffu + ((x >> 16) & 1u)) >> 16);
}

// ---------------- f32 -> bf16 conversion (n % 4 == 0) ----------------
__global__ void k_cvt(const float* __restrict__ s, bf16_t* __restrict__ d, int n) {
  int i = (blockIdx.x * blockDim.x + threadIdx.x) * 4;
  if (i >= n) return;
  float4 v = *reinterpret_cast<const float4*>(&s[i]);
  uint2 o;
  o.x = (unsigned)f2bf(v.x) | ((unsigned)f2bf(v.y) << 16);
  o.y = (unsigned)f2bf(v.z) | ((unsigned)f2bf(v.w) << 16);
  *reinterpret_cast<uint2*>(&d[i]) = o;
}

// merged conversion of the 5 weight tensors (one launch)
#define W0N 32768            // pre_w 256*128
#define W1N 196608           // lin_l_w 3*256*256
#define W2N 196608           // lin_r_w
#define W3N 65536            // post1_w
#define W4N 10240            // post2_w 40*256
#define WTOT (W0N + W1N + W2N + W3N + W4N)

__global__ void k_cvt_w(const float* __restrict__ s0, bf16_t* __restrict__ d0,
                        const float* __restrict__ s1, bf16_t* __restrict__ d1,
                        const float* __restrict__ s2, bf16_t* __restrict__ d2,
                        const float* __restrict__ s3, bf16_t* __restrict__ d3,
                        const float* __restrict__ s4, bf16_t* __restrict__ d4) {
  int i = (blockIdx.x * blockDim.x + threadIdx.x) * 4;
  if (i >= WTOT) return;
  const float* s; bf16_t* d;
  if (i < W0N)                         { s = s0; d = d0; }
  else if (i < W0N + W1N)              { s = s1; d = d1; i -= W0N; }
  else if (i < W0N + W1N + W2N)        { s = s2; d = d2; i -= W0N + W1N; }
  else if (i < W0N + W1N + W2N + W3N)  { s = s3; d = d3; i -= W0N + W1N + W2N; }
  else                                 { s = s4; d = d4; i -= W0N + W1N + W2N + W3N; }
  float4 v = *reinterpret_cast<const float4*>(&s[i]);
  uint2 o;
  o.x = (unsigned)f2bf(v.x) | ((unsigned)f2bf(v.y) << 16);
  o.y = (unsigned)f2bf(v.z) | ((unsigned)f2bf(v.w) << 16);
  *reinterpret_cast<uint2*>(&d[i]) = o;
}

// ---------------- CSR build (merged hist+rank, atomic-free placement) -------
__global__ void k_rank(const int* __restrict__ dst, int* __restrict__ cursor,
                       int* __restrict__ rank, int E) {
  for (int e = blockIdx.x * blockDim.x + threadIdx.x; e < E; e += gridDim.x * blockDim.x)
    rank[e] = atomicAdd(&cursor[dst[e]], 1);
}

__global__ __launch_bounds__(1024)
void k_scan_local(const int* __restrict__ cnt, int* __restrict__ row_ptr,
                  int* __restrict__ blk_sum, int n) {
  __shared__ int buf[1024];
  int tid = threadIdx.x;
  int i = blockIdx.x * 1024 + tid;
  int v = (i < n) ? cnt[i] : 0;
  buf[tid] = v;
  __syncthreads();
  for (int off = 1; off < 1024; off <<= 1) {
    int t = (tid >= off) ? buf[tid - off] : 0;
    __syncthreads();
    buf[tid] += t;
    __syncthreads();
  }
  if (i < n) row_ptr[i] = buf[tid] - v;       // block-local exclusive
  if (tid == 1023) blk_sum[blockIdx.x] = buf[1023];
}

__global__ __launch_bounds__(128)
void k_scan_blk(const int* __restrict__ blk_sum, int* __restrict__ blk_off, int nb) {
  __shared__ int buf[128];
  int tid = threadIdx.x;
  int v = (tid < nb) ? blk_sum[tid] : 0;
  buf[tid] = v;
  __syncthreads();
  for (int off = 1; off < 128; off <<= 1) {
    int t = (tid >= off) ? buf[tid - off] : 0;
    __syncthreads();
    buf[tid] += t;
    __syncthreads();
  }
  if (tid < nb) blk_off[tid] = buf[tid] - v;  // exclusive
}

// adds block offsets AND computes inv_deg (folded k_inv)
__global__ void k_scan_add(int* __restrict__ row_ptr, const int* __restrict__ blk_off,
                           const int* __restrict__ cnt, float* __restrict__ inv, int n) {
  int i = blockIdx.x * blockDim.x + threadIdx.x;
  if (i < n) {
    row_ptr[i] += blk_off[i >> 10];
    int c = cnt[i];
    inv[i] = 1.0f / (float)(c > 0 ? c : 1);
  }
  if (i == 0) row_ptr[n] = N_EDGES;
}

__global__ void k_place(const int* __restrict__ src, const int* __restrict__ dst,
                        const int* __restrict__ rank, const int* __restrict__ row_ptr,
                        int* __restrict__ csr, int E) {
  for (int e = blockIdx.x * blockDim.x + threadIdx.x; e < E; e += gridDim.x * blockDim.x)
    csr[row_ptr[dst[e]] + rank[e]] = src[e];
}

// ---------------- mean aggregation ----------------
__device__ __forceinline__ void add8(float* acc, uint4 r) {
  acc[0] += bf2f(r.x & 0xffffu); acc[1] += bf2f(r.x >> 16);
  acc[2] += bf2f(r.y & 0xffffu); acc[3] += bf2f(r.y >> 16);
  acc[4] += bf2f(r.z & 0xffffu); acc[5] += bf2f(r.z >> 16);
  acc[6] += bf2f(r.w & 0xffffu); acc[7] += bf2f(r.w >> 16);
}

__global__ __launch_bounds__(256)
void k_aggregate(const bf16_t* __restrict__ h, const int* __restrict__ row_ptr,
                 const int* __restrict__ csr, const float* __restrict__ inv_deg,
                 bf16_t* __restrict__ mean) {
  int w = threadIdx.x >> 6, lane = threadIdx.x & 63;
  int node = blockIdx.x * 4 + w;
  if (node >= N_NODES) return;
  int beg = row_ptr[node], end = row_ptr[node + 1];
  int half = lane >> 5;         // 0 or 1: which edge of the pair
  int l32 = lane & 31;          // 16B column block within the row
  float acc[8] = {};
  int deg = end - beg;
  int p = beg;
  int p8 = beg + (deg & ~7);
  for (; p < p8; p += 8) {       // 8 edges per iteration, 4 row loads/lane in flight
    int s0 = csr[p + half];
    int s1 = csr[p + 2 + half];
    int s2 = csr[p + 4 + half];
    int s3 = csr[p + 6 + half];
    uint4 r0 = *reinterpret_cast<const uint4*>(&h[(size_t)s0 * HDIM + l32 * 8]);
    uint4 r1 = *reinterpret_cast<const uint4*>(&h[(size_t)s1 * HDIM + l32 * 8]);
    uint4 r2 = *reinterpret_cast<const uint4*>(&h[(size_t)s2 * HDIM + l32 * 8]);
    uint4 r3 = *reinterpret_cast<const uint4*>(&h[(size_t)s3 * HDIM + l32 * 8]);
    add8(acc, r0);
    add8(acc, r1);
    add8(acc, r2);
    add8(acc, r3);
  }
  if (end - p >= 4) {            // 4-edge block: 2 row loads in flight
    int s0 = csr[p + half];
    int s1 = csr[p + 2 + half];
    uint4 r0 = *reinterpret_cast<const uint4*>(&h[(size_t)s0 * HDIM + l32 * 8]);
    uint4 r1 = *reinterpret_cast<const uint4*>(&h[(size_t)s1 * HDIM + l32 * 8]);
    add8(acc, r0);
    add8(acc, r1);
    p += 4;
  }
  for (; p < end; p += 2) {      // tail: <=3 edges, pair-guarded
    int e = p + half;
    if (e < end) {
      int s = csr[e];
      uint4 r = *reinterpret_cast<const uint4*>(&h[(size_t)s * HDIM + l32 * 8]);
      add8(acc, r);
    }
  }
#pragma unroll
  for (int k = 0; k < 8; ++k) acc[k] += __shfl_xor(acc[k], 32);
  if (half == 0) {
    float iv = inv_deg[node];
    uint4 o;
    o.x = (unsigned)f2bf(acc[0] * iv) | ((unsigned)f2bf(acc[1] * iv) << 16);
    o.y = (unsigned)f2bf(acc[2] * iv) | ((unsigned)f2bf(acc[3] * iv) << 16);
    o.z = (unsigned)f2bf(acc[4] * iv) | ((unsigned)f2bf(acc[5] * iv) << 16);
    o.w = (unsigned)f2bf(acc[6] * iv) | ((unsigned)f2bf(acc[7] * iv) << 16);
    *reinterpret_cast<uint4*>(&mean[(size_t)node * HDIM + l32 * 8]) = o;
  }
}

// ---------------- output store helpers ----------------
__device__ __forceinline__ void store1(float* p, float v) { *p = v; }
__device__ __forceinline__ void store1(bf16_t* p, float v) { *p = f2bf(v); }

// ---------------- bf16 MFMA GEMM, gload_lds + XOR slot-swizzle --------------
// C[M,OUT] = act( A0 @ W0^T (+ A1 @ W1^T) + bias ), W row-major [OUT,K] bf16.
// 128x128 tile, BK=32, 4 waves (2x2), 4x4 frags of 16x16x32 per wave.
// Grid: 1-D. For OUT=256 the two column-tiles of row-panel x are placed 8
// dispatch slots apart -> same XCD under round-robin -> A panel read once
// into that XCD's L2 (T1 co-location). For OUT<=128: g == row tile.
// LDS slot-swizzle: same involution on source k-slot and read slot (rule #21).
// fuse_lsm: epilogue computes row log-softmax (OUT=40) and writes directly
// to the output — all 40 cols live in waves wn==0 as 3 j-groups x 16 lanes;
// row is uniform within each 16-lane group so shfl_xor(8..1) reduces the row.
template <typename TOUT>
__global__ __launch_bounds__(256)
void gemm_mfma(const bf16_t* __restrict__ A0, const bf16_t* __restrict__ W0,
               const bf16_t* __restrict__ A1, const bf16_t* __restrict__ W1,
               const float* __restrict__ bias, const float* __restrict__ bn,
               TOUT* __restrict__ C, int M, int K, int OUT, int dual, int fuse_lsm) {
  __shared__ bf16_t lds[2][2][128 * 32];   // [buf][A/B][row*32+k]
  int g = blockIdx.x, bx, by;
  if (OUT > 128) {                // co-locate (x,0) and (x,1): slots g and g+8
    int grp = g >> 4, loc = g & 15;
    bx = grp * 8 + (loc & 7);
    by = loc >> 3;
  } else {
    bx = g; by = 0;
  }
  const int row0 = bx * 128, col0 = by * 128;
  if (row0 >= M) return;          // uniform per block (pad blocks)

  const int tid = threadIdx.x;
  const int lane = tid & 63, wid = tid >> 6;
  const int wm = wid >> 1, wn = wid & 1;
  const int l15 = lane & 15, l4 = lane >> 4;

  const int nk = K / 32;
  const int nsteps = dual ? nk * 2 : nk;

  f32x4 acc[4][4] = {};

  const int srow_base = wid * 32 + (lane >> 2);
  const int skk = ((lane & 3) ^ ((lane >> 3) & 3)) * 8;   // swizzled source k-slot

  auto stage = [&](int s, int b) {
    const bf16_t* A = (s < nk) ? A0 : A1;
    const bf16_t* W = (s < nk) ? W0 : W1;
    int kk0 = ((s < nk) ? s : s - nk) * 32 + skk;
#pragma unroll
    for (int c = 0; c < 2; ++c) {
      int chunk = wid * 2 + c;            // 0..7
      int row = srow_base + c * 16;       // chunk*16 + lane/4
      int ar = row0 + row; if (ar >= M) ar = M - 1;
      int br = col0 + row; if (br >= OUT) br = OUT - 1;
      __builtin_amdgcn_global_load_lds(
          (const __attribute__((address_space(1))) unsigned int*)&A[(size_t)ar * K + kk0],
          (__attribute__((address_space(3))) unsigned int*)&lds[b][0][chunk * 512],
          16, 0, 0);
      __builtin_amdgcn_global_load_lds(
          (const __attribute__((address_space(1))) unsigned int*)&W[(size_t)br * K + kk0],
          (__attribute__((address_space(3))) unsigned int*)&lds[b][1][chunk * 512],
          16, 0, 0);
    }
  };

  const int rslot = (l4 ^ ((l15 >> 1) & 3)) * 8;

  stage(0, 0);
  __syncthreads();               // drains vmcnt(0): buffer 0 ready
  int cur = 0;
  for (int s = 0; s < nsteps; ++s) {
    if (s + 1 < nsteps) stage(s + 1, cur ^ 1);   // async into other buffer
    const bf16_t* pa = &lds[cur][0][l15 * 32 + rslot];
    const bf16_t* pb = &lds[cur][1][l15 * 32 + rslot];
    bf16x8 a[4], b[4];
#pragma unroll
    for (int i = 0; i < 4; ++i)
      a[i] = *reinterpret_cast<const bf16x8*>(&pa[(wm * 64 + i * 16) * 32]);
#pragma unroll
    for (int j = 0; j < 4; ++j)
      b[j] = *reinterpret_cast<const bf16x8*>(&pb[(wn * 64 + j * 16) * 32]);
#pragma unroll
    for (int i = 0; i < 4; ++i)
#pragma unroll
      for (int j = 0; j < 4; ++j)
        acc[i][j] = __builtin_amdgcn_mfma_f32_16x16x32_bf16(a[i], b[j], acc[i][j], 0, 0, 0);
    if (s + 1 < nsteps) {
      __syncthreads();           // all reads of cur done AND staged buffer drained
      cur ^= 1;
    }
  }

  if (fuse_lsm) {
    // row log-softmax epilogue (OUT == 40, bn == null). Only wn==0 has cols.
    if (wn == 0) {
#pragma unroll
      for (int i = 0; i < 4; ++i) {
#pragma unroll
        for (int r = 0; r < 4; ++r) {
          int row = row0 + wm * 64 + i * 16 + l4 * 4 + r;   // uniform in l15-group
          if (row >= M) continue;
          float v[3];
          float mx = -1e30f;
#pragma unroll
          for (int j = 0; j < 3; ++j) {
            int col = j * 16 + l15;
            v[j] = acc[i][j][r] + bias[col < OUT ? col : 0];
            if (col < OUT) mx = fmaxf(mx, v[j]);
          }
#pragma unroll
          for (int o = 8; o; o >>= 1) mx = fmaxf(mx, __shfl_xor(mx, o));
          float sm = 0.f;
#pragma unroll
          for (int j = 0; j < 3; ++j) {
            int col = j * 16 + l15;
            if (col < OUT) sm += expf(v[j] - mx);
          }
#pragma unroll
          for (int o = 8; o; o >>= 1) sm += __shfl_xor(sm, o);
          float ls = logf(sm);
#pragma unroll
          for (int j = 0; j < 3; ++j) {
            int col = j * 16 + l15;
            if (col < OUT)
              store1(&C[(size_t)row * OUT + col], v[j] - mx - ls);
          }
        }
      }
    }
    return;
  }

  // epilogue: C/D frag mapping col=lane&15, row=(lane>>4)*4+reg  [m89]
#pragma unroll
  for (int j = 0; j < 4; ++j) {
    int col = col0 + wn * 64 + j * 16 + l15;
    if (col >= OUT) continue;
    float bs = bias ? bias[col] : 0.f;
    float scale = 1.f, shift = bs;
    bool has_bn = (bn != nullptr);
    if (has_bn) {
      float g2 = bn[col], bb = bn[256 + col], mm = bn[512 + col], vv = bn[768 + col];
      float is = g2 * rsqrtf(vv + BN_EPS);
      scale = is; shift = (bs - mm) * is + bb;
    }
#pragma unroll
    for (int i = 0; i < 4; ++i) {
#pragma unroll
      for (int r = 0; r < 4; ++r) {
        int row = row0 + wm * 64 + i * 16 + l4 * 4 + r;
        if (row >= M) continue;
        float v = acc[i][j][r];
        v = has_bn ? fmaxf(v * scale + shift, 0.f) : (v + bs);
        store1(&C[(size_t)row * OUT + col], v);
      }
    }
  }
}

// ---------------- host launch ----------------
extern "C" void kernel_launch(void* const* d_in, const int* in_sizes, int n_in,
                              void* d_out, int out_size, void* d_ws, size_t ws_size,
                              hipStream_t stream) {
  const float* x       = (const float*)d_in[0];
  const int*   ei      = (const int*)d_in[1];   // [2, E] int32
  const float* pre_w   = (const float*)d_in[2];
  const float* pre_b   = (const float*)d_in[3];
  const float* bn      = (const float*)d_in[4]; // [5,4,256]
  const float* lin_l_w = (const float*)d_in[5];
  const float* lin_l_b = (const float*)d_in[6];
  const float* lin_r_w = (const float*)d_in[7];
  const float* post1_w = (const float*)d_in[8];
  const float* post1_b = (const float*)d_in[9];
  const float* post2_w = (const float*)d_in[10];
  const float* post2_b = (const float*)d_in[11];
  float* out = (float*)d_out;

  const int* src = ei;
  const int* dstv = ei + N_EDGES;

  char* base = (char*)d_ws;
  size_t off = 0;
  auto alloc = [&](size_t bytes) -> void* {
    void* p = base + off;
    off = (off + bytes + 255) & ~(size_t)255;
    return p;
  };
  bf16_t* hA = (bf16_t*)alloc((size_t)N_NODES * HDIM * 2);
  bf16_t* hB = (bf16_t*)alloc((size_t)N_NODES * HDIM * 2);  // x_bf16 pre-GEMM
  bf16_t* hC = (bf16_t*)alloc((size_t)N_NODES * HDIM * 2);
  int* row_ptr = (int*)alloc((size_t)(N_NODES + 1) * 4);
  int* cursor  = (int*)alloc((size_t)N_NODES * 4);   // doubles as per-node degree after k_rank
  int* csr     = (int*)alloc((size_t)N_EDGES * 4);
  int* rank    = (int*)alloc((size_t)N_EDGES * 4);
  float* inv   = (float*)alloc((size_t)N_NODES * 4);
  int* blk_sum = (int*)alloc(128 * 4);
  int* blk_off = (int*)alloc(128 * 4);
  bf16_t* w_pre = (bf16_t*)alloc((size_t)HDIM * F_INDIM * 2);
  bf16_t* w_ll  = (bf16_t*)alloc((size_t)3 * HDIM * HDIM * 2);
  bf16_t* w_lr  = (bf16_t*)alloc((size_t)3 * HDIM * HDIM * 2);
  bf16_t* w_p1  = (bf16_t*)alloc((size_t)HDIM * HDIM * 2);
  bf16_t* w_p2  = (bf16_t*)alloc((size_t)C_OUT * HDIM * 2);
  (void)n_in; (void)in_sizes; (void)out_size;
  if (off > ws_size) return;  // visible failure (zeros), no fault

  bf16_t* x_bf = hB;

  // input + weight conversions (x separate; 5 weights merged into one launch)
  {
    int n = N_NODES * F_INDIM;
    k_cvt<<<(n / 4 + 255) / 256, 256, 0, stream>>>(x, x_bf, n);
    k_cvt_w<<<(WTOT / 4 + 255) / 256, 256, 0, stream>>>(
        pre_w, w_pre, lin_l_w, w_ll, lin_r_w, w_lr, post1_w, w_p1, post2_w, w_p2);
  }

  // CSR build: one atomic pass (rank+hist), scan (+inv fold), atomic-free placement
  hipMemsetAsync(cursor, 0, (size_t)N_NODES * 4, stream);
  k_rank<<<2048, 256, 0, stream>>>(dstv, cursor, rank, N_EDGES);
  int nb = (N_NODES + 1023) / 1024;  // 98
  k_scan_local<<<nb, 1024, 0, stream>>>(cursor, row_ptr, blk_sum, N_NODES);
  k_scan_blk<<<1, 128, 0, stream>>>(blk_sum, blk_off, nb);
  k_scan_add<<<(N_NODES + 255) / 256, 256, 0, stream>>>(row_ptr, blk_off, cursor, inv, N_NODES);
  k_place<<<2048, 256, 0, stream>>>(src, dstv, rank, row_ptr, csr, N_EDGES);

  // grids: OUT=256 -> 1-D swizzled (98 groups x 16); OUT=40 -> plain 782
  int nrt = (N_NODES + 127) / 128;          // 782
  int gW = ((nrt + 7) / 8) * 16;            // 1568
  // pre: h = relu(bn0(x @ pre_w^T + pre_b))
  gemm_mfma<bf16_t><<<gW, 256, 0, stream>>>(
      x_bf, w_pre, nullptr, nullptr, pre_b, bn, hA, N_NODES, F_INDIM, HDIM, 0, 0);

  bf16_t* hcur = hA;
  bf16_t* hnext = hC;
  for (int i = 0; i < 3; ++i) {
    k_aggregate<<<N_NODES / 4, 256, 0, stream>>>(hcur, row_ptr, csr, inv, hB);
    gemm_mfma<bf16_t><<<gW, 256, 0, stream>>>(
        hB, w_ll + (size_t)i * HDIM * HDIM,
        hcur, w_lr + (size_t)i * HDIM * HDIM,
        lin_l_b + (size_t)i * HDIM,
        bn + (size_t)(i + 1) * 4 * HDIM,
        hnext, N_NODES, HDIM, HDIM, 1, 0);
    bf16_t* t = hcur; hcur = hnext; hnext = t;
  }
  // post1
  gemm_mfma<bf16_t><<<gW, 256, 0, stream>>>(
      hcur, w_p1, nullptr, nullptr, post1_b,
      bn + (size_t)4 * 4 * HDIM, hnext, N_NODES, HDIM, HDIM, 0, 0);
  // post2 + fused log-softmax -> out
  gemm_mfma<float><<<nrt, 256, 0, stream>>>(
      hnext, w_p2, nullptr, nullptr, post2_b,
      nullptr, out, N_NODES, HDIM, C_OUT, 0, 1);
}